// Round 10
// baseline (222.032 us; speedup 1.0000x reference)
//
#include <hip/hip_runtime.h>
#include <stdint.h>

// PerfeCT membership: out[i] = +5.0 if (h,r,t) appears in data, else -5.0.
// key32 = ((h*15000+r)*15000+t) mod 2^32 (replicates reference's int32 overflow).
// r8 diagnosis: dur_us INCLUDES harness ws-poison (480MB fill = 68us) + d_in restore
// (~34us) -> ~105us fixed floor. k_scan (~50-70us) is MLP-limited: 6 loads/wave-iter,
// 16 waves/CU vs ~64-line miss buffer and 400-900cyc latency. Fix: 4 streams x int4
// = 12 loads in flight; drop ovf list (inline-probe fallback, ~300 events); 4 kernels.

typedef int iv4 __attribute__((ext_vector_type(4)));

#define EMPTY  0xFFFFFFFFu
#define BWORDS 32768     // 2^20-bit bloom = 128 KB LDS
#define QSLOTS 6
#define TPB    1024

static __device__ __forceinline__ uint32_t mix32(uint32_t x) {
    x ^= x >> 16; x *= 0x85ebca6bu;
    x ^= x >> 13; x *= 0xc2b2ae35u;
    x ^= x >> 16;
    return x;
}
static __device__ __forceinline__ uint32_t hash2(uint32_t x) {   // exact-table hash (cold path)
    return mix32(x ^ 0x9E3779B9u);
}
static __device__ __forceinline__ uint32_t key32(int h, int r, int t) {
    return ((uint32_t)h * 15000u + (uint32_t)r) * 15000u + (uint32_t)t;
}
static __device__ __forceinline__ void bloom_wm(uint32_t key, uint32_t* w, uint32_t* m) {
    uint32_t z = mix32(key);
    *w = z & (BWORDS - 1u);
    *m = (1u << ((z >> 15) & 31u)) | (1u << ((z >> 20) & 31u));
}

// ws: [bloom 128KB][flagbits (1<<tb)/8][hdr 256B: sent@0][keys 4<<tb]
__global__ void k_zero(uint32_t* __restrict__ p, int zeroWords, int totalWords) {
    int stride = gridDim.x * blockDim.x;
    for (int i = blockIdx.x * blockDim.x + threadIdx.x; i < totalWords; i += stride)
        p[i] = (i < zeroWords) ? 0u : EMPTY;
}

__global__ void k_insert(const int* __restrict__ qh, const int* __restrict__ qr,
                         const int* __restrict__ qt,
                         uint32_t* __restrict__ bloom, uint32_t* __restrict__ keys,
                         uint32_t tmask, int Q) {
    int i = blockIdx.x * blockDim.x + threadIdx.x;
    if (i >= Q) return;
    uint32_t key = key32(qh[i], qr[i], qt[i]);
    if (key == EMPTY) return;       // sentinel-valued query: k_out consults `sent`
    uint32_t w, m; bloom_wm(key, &w, &m);
    atomicOr(&bloom[w], m);
    uint32_t slot = hash2(key) & tmask;
    while (true) {
        uint32_t prev = atomicCAS(&keys[slot], EMPTY, key);
        if (prev == EMPTY || prev == key) return;
        slot = (slot + 1) & tmask;
    }
}

static __device__ __forceinline__ void probe_mark(uint32_t key,
                                                  const uint32_t* __restrict__ keys,
                                                  uint32_t* __restrict__ flagbits,
                                                  uint32_t tmask) {
    uint32_t slot = hash2(key) & tmask;
    while (true) {
        uint32_t v = keys[slot];
        if (v == key) { atomicOr(&flagbits[slot >> 5], 1u << (slot & 31)); return; }
        if (v == EMPTY) return;
        slot = (slot + 1) & tmask;
    }
}

// One block/CU, 152 KB LDS. 16 triples/thread-iter via 4 independent int4 streams
// (12 loads in flight). Bloom hits -> per-lane LDS queue, drained post-loop;
// queue overflow (P~0.07%/thread) falls back to an inline probe.
__global__ __launch_bounds__(TPB) void k_scan(
        const int* __restrict__ dh, const int* __restrict__ dr,
        const int* __restrict__ dt,
        const uint32_t* __restrict__ bloom,
        const uint32_t* __restrict__ keys,
        uint32_t* __restrict__ flagbits, uint32_t* __restrict__ sent,
        uint32_t tmask, int nhex, int N) {
    __shared__ uint32_t lb[BWORDS];          // 128 KB
    __shared__ uint32_t qb[TPB * QSLOTS];    // 24 KB, slot-major (conflict-free)
    {
        const iv4* gb = (const iv4*)bloom;   // vectorized fill: 8 x int4 per thread
        iv4* lb4 = (iv4*)lb;
        for (int i = threadIdx.x; i < BWORDS / 4; i += TPB) lb4[i] = gb[i];
    }
    __syncthreads();

    const iv4* H = (const iv4*)dh;
    const iv4* R = (const iv4*)dr;
    const iv4* T = (const iv4*)dt;
    int cnt = 0;
    int stride = gridDim.x * blockDim.x;

#define TESTQ(kk, vv, mm)                                                          \
    if ((kk) == EMPTY) *sent = 1u;                                                 \
    else if (((vv) & (mm)) == (mm)) {                                              \
        if (cnt < QSLOTS) { qb[cnt * TPB + threadIdx.x] = (kk); cnt++; }           \
        else probe_mark((kk), keys, flagbits, tmask);                              \
    }
#define GRP4(h4, r4, t4)                                                           \
    {                                                                              \
        uint32_t k0 = key32((h4).x, (r4).x, (t4).x), k1 = key32((h4).y, (r4).y, (t4).y); \
        uint32_t k2 = key32((h4).z, (r4).z, (t4).z), k3 = key32((h4).w, (r4).w, (t4).w); \
        uint32_t w0,m0,w1,m1,w2,m2,w3,m3;                                          \
        bloom_wm(k0,&w0,&m0); bloom_wm(k1,&w1,&m1);                                \
        bloom_wm(k2,&w2,&m2); bloom_wm(k3,&w3,&m3);                                \
        uint32_t v0 = lb[w0], v1 = lb[w1], v2 = lb[w2], v3 = lb[w3];               \
        TESTQ(k0, v0, m0) TESTQ(k1, v1, m1) TESTQ(k2, v2, m2) TESTQ(k3, v3, m3)    \
    }

    for (int j = blockIdx.x * blockDim.x + threadIdx.x; j < nhex; j += stride) {
        // issue all 12 independent loads before any consume (MLP 12)
        iv4 hA = H[j], hB = H[j + nhex], hC = H[j + 2 * nhex], hD = H[j + 3 * nhex];
        iv4 rA = R[j], rB = R[j + nhex], rC = R[j + 2 * nhex], rD = R[j + 3 * nhex];
        iv4 tA = T[j], tB = T[j + nhex], tC = T[j + 2 * nhex], tD = T[j + 3 * nhex];
        GRP4(hA, rA, tA) GRP4(hB, rB, tB) GRP4(hC, rC, tC) GRP4(hD, rD, tD)
    }
#undef GRP4
#undef TESTQ

    // leftover elements [16*nhex, N) — at most 15
    int rem = N - 16 * nhex;
    if (blockIdx.x == 0 && (int)threadIdx.x < rem) {
        int j = 16 * nhex + threadIdx.x;
        uint32_t k = key32(dh[j], dr[j], dt[j]);
        if (k == EMPTY) *sent = 1u;
        else probe_mark(k, keys, flagbits, tmask);
    }

    // drain per-lane queue (all waves concurrently -> latency hidden by TLP)
    int m = cnt < QSLOTS ? cnt : QSLOTS;
    for (int c = 0; c < m; ++c)
        probe_mark(qb[c * TPB + threadIdx.x], keys, flagbits, tmask);
}

__global__ void k_out(const int* __restrict__ qh, const int* __restrict__ qr,
                      const int* __restrict__ qt,
                      const uint32_t* __restrict__ keys,
                      const uint32_t* __restrict__ flagbits,
                      const uint32_t* __restrict__ sent,
                      float* __restrict__ out, uint32_t tmask, int Q) {
    int i = blockIdx.x * blockDim.x + threadIdx.x;
    if (i >= Q) return;
    uint32_t key = key32(qh[i], qr[i], qt[i]);
    float v = -5.0f;
    if (key == EMPTY) {
        v = (*sent) ? 5.0f : -5.0f;
    } else {
        uint32_t slot = hash2(key) & tmask;
        while (true) {
            uint32_t kv = keys[slot];
            if (kv == key) { v = ((flagbits[slot >> 5] >> (slot & 31)) & 1u) ? 5.0f : -5.0f; break; }
            if (kv == EMPTY) break;
            slot = (slot + 1) & tmask;
        }
    }
    out[i] = v;
}

extern "C" void kernel_launch(void* const* d_in, const int* in_sizes, int n_in,
                              void* d_out, int out_size, void* d_ws, size_t ws_size,
                              hipStream_t stream) {
    const int* qh = (const int*)d_in[0];
    const int* qr = (const int*)d_in[1];
    const int* qt = (const int*)d_in[2];
    const int* data = (const int*)d_in[3];
    int Q = in_sizes[0];
    int N = in_sizes[3] / 3;
    const int* dh = data;
    const int* dr = data + (size_t)N;
    const int* dt = data + 2 * (size_t)N;
    float* out = (float*)d_out;

    int tb = 18;                               // 100K keys, alpha 0.38; floor 17 (livelock guard)
    size_t bloomB = (size_t)BWORDS * 4;        // 128 KB
    size_t need = bloomB + ((size_t)1 << (tb - 3)) + 256 + ((size_t)4 << tb);
    if (need > ws_size) tb = 17;
    size_t flagB = (size_t)1 << (tb - 3);
    uint32_t tmask = ((uint32_t)1 << tb) - 1u;

    uint32_t* bloom    = (uint32_t*)d_ws;
    uint32_t* flagbits = (uint32_t*)((char*)d_ws + bloomB);
    uint32_t* hdr      = (uint32_t*)((char*)d_ws + bloomB + flagB);     // sent@0
    uint32_t* keys     = (uint32_t*)((char*)d_ws + bloomB + flagB + 256);

    int zeroWords  = (int)((bloomB + flagB + 256) / 4);
    int totalWords = zeroWords + (1 << tb);
    k_zero<<<1024, 256, 0, stream>>>((uint32_t*)d_ws, zeroWords, totalWords);

    int qblocks = (Q + 255) / 256;
    k_insert<<<qblocks, 256, 0, stream>>>(qh, qr, qt, bloom, keys, tmask, Q);

    int nhex = N / 16;
    k_scan<<<256, TPB, 0, stream>>>(dh, dr, dt, bloom, keys, flagbits,
                                    hdr, tmask, nhex, N);

    k_out<<<qblocks, 256, 0, stream>>>(qh, qr, qt, keys, flagbits, hdr, out, tmask, Q);
}

// Round 11
// 209.315 us; speedup vs baseline: 1.0608x; 1.0608x over previous
//
#include <hip/hip_runtime.h>
#include <stdint.h>

// PerfeCT membership: out[i] = +5.0 if (h,r,t) appears in data, else -5.0.
// key32 = ((h*15000+r)*15000+t) mod 2^32 (replicates reference's int32 overflow).
// r10 diagnosis: per-wave MLP 6->12 NEUTRAL (220->222) -> not outstanding-load bound.
// k_scan ~60us = 2.5 TB/s aggregate; only 16 waves/CU (128KB LDS bloom + 24KB LDS
// queue = 1 block/CU). This round: bloom 64KB (2^19 bits) + register shift-queue
// -> 2 blocks/CU = 32 waves/CU (double TLP). FP 3.6%->10% (probes stay deferred,
// L2-resident). __launch_bounds__(1024,8) caps VGPR<=64 so 2 blocks co-reside.
// Data loads nontemporal (read-once semantics).

typedef int iv4 __attribute__((ext_vector_type(4)));

#define EMPTY  0xFFFFFFFFu
#define BWORDS 16384     // 2^19-bit bloom = 64 KB LDS
#define TPB    1024

static __device__ __forceinline__ uint32_t mix32(uint32_t x) {
    x ^= x >> 16; x *= 0x85ebca6bu;
    x ^= x >> 13; x *= 0xc2b2ae35u;
    x ^= x >> 16;
    return x;
}
static __device__ __forceinline__ uint32_t hash2(uint32_t x) {   // exact-table hash (cold path)
    return mix32(x ^ 0x9E3779B9u);
}
static __device__ __forceinline__ uint32_t key32(int h, int r, int t) {
    return ((uint32_t)h * 15000u + (uint32_t)r) * 15000u + (uint32_t)t;
}
// Blocked bloom in 2^19 bits: word = z[13:0], two bit positions from z[18:14], z[23:19].
static __device__ __forceinline__ void bloom_wm(uint32_t key, uint32_t* w, uint32_t* m) {
    uint32_t z = mix32(key);
    *w = z & (BWORDS - 1u);
    *m = (1u << ((z >> 14) & 31u)) | (1u << ((z >> 19) & 31u));
}

// ws: [bloom 64KB][flagbits (1<<tb)/8][hdr 256B: sent@0][keys 4<<tb]
__global__ void k_zero(uint32_t* __restrict__ p, int zeroWords, int totalWords) {
    int stride = gridDim.x * blockDim.x;
    for (int i = blockIdx.x * blockDim.x + threadIdx.x; i < totalWords; i += stride)
        p[i] = (i < zeroWords) ? 0u : EMPTY;
}

__global__ void k_insert(const int* __restrict__ qh, const int* __restrict__ qr,
                         const int* __restrict__ qt,
                         uint32_t* __restrict__ bloom, uint32_t* __restrict__ keys,
                         uint32_t tmask, int Q) {
    int i = blockIdx.x * blockDim.x + threadIdx.x;
    if (i >= Q) return;
    uint32_t key = key32(qh[i], qr[i], qt[i]);
    if (key == EMPTY) return;       // sentinel-valued query: k_out consults `sent`
    uint32_t w, m; bloom_wm(key, &w, &m);
    atomicOr(&bloom[w], m);
    uint32_t slot = hash2(key) & tmask;
    while (true) {
        uint32_t prev = atomicCAS(&keys[slot], EMPTY, key);
        if (prev == EMPTY || prev == key) return;
        slot = (slot + 1) & tmask;
    }
}

static __device__ __forceinline__ void probe_mark(uint32_t key,
                                                  const uint32_t* __restrict__ keys,
                                                  uint32_t* __restrict__ flagbits,
                                                  uint32_t tmask) {
    uint32_t slot = hash2(key) & tmask;
    while (true) {
        uint32_t v = keys[slot];
        if (v == key) { atomicOr(&flagbits[slot >> 5], 1u << (slot & 31)); return; }
        if (v == EMPTY) return;
        slot = (slot + 1) & tmask;
    }
}

// 2 blocks/CU (64KB LDS each) = 32 waves/CU. 8 triples/thread-iter via 2 int4
// streams (6 NT loads in flight). Bloom hits -> 6-deep REGISTER shift-queue
// (static indices), drained post-loop; overflow (P~0.2%) inline-probes.
__global__ __launch_bounds__(TPB, 8) void k_scan(
        const int* __restrict__ dh, const int* __restrict__ dr,
        const int* __restrict__ dt,
        const uint32_t* __restrict__ bloom,
        const uint32_t* __restrict__ keys,
        uint32_t* __restrict__ flagbits, uint32_t* __restrict__ sent,
        uint32_t tmask, int n8, int N) {
    __shared__ uint32_t lb[BWORDS];          // 64 KB
    {
        const iv4* gb = (const iv4*)bloom;   // 4 x int4 per thread
        iv4* lb4 = (iv4*)lb;
        for (int i = threadIdx.x; i < BWORDS / 4; i += TPB) lb4[i] = gb[i];
    }
    __syncthreads();

    const iv4* H = (const iv4*)dh;
    const iv4* R = (const iv4*)dr;
    const iv4* T = (const iv4*)dt;
    int cnt = 0;
    uint32_t q0 = 0, q1 = 0, q2 = 0, q3 = 0, q4 = 0, q5 = 0;
    int stride = gridDim.x * blockDim.x;

#define TESTQ(kk, vv, mm)                                                          \
    if ((kk) == EMPTY) *sent = 1u;                                                 \
    else if (((vv) & (mm)) == (mm)) {                                              \
        if (cnt < 6) { q5 = q4; q4 = q3; q3 = q2; q2 = q1; q1 = q0; q0 = (kk); cnt++; } \
        else probe_mark((kk), keys, flagbits, tmask);                              \
    }
#define GRP4(h4, r4, t4)                                                           \
    {                                                                              \
        uint32_t k0 = key32((h4).x, (r4).x, (t4).x), k1 = key32((h4).y, (r4).y, (t4).y); \
        uint32_t k2 = key32((h4).z, (r4).z, (t4).z), k3 = key32((h4).w, (r4).w, (t4).w); \
        uint32_t w0,m0,w1,m1,w2,m2,w3,m3;                                          \
        bloom_wm(k0,&w0,&m0); bloom_wm(k1,&w1,&m1);                                \
        bloom_wm(k2,&w2,&m2); bloom_wm(k3,&w3,&m3);                                \
        uint32_t v0 = lb[w0], v1 = lb[w1], v2 = lb[w2], v3 = lb[w3];               \
        TESTQ(k0, v0, m0) TESTQ(k1, v1, m1) TESTQ(k2, v2, m2) TESTQ(k3, v3, m3)    \
    }

    for (int j = blockIdx.x * blockDim.x + threadIdx.x; j < n8; j += stride) {
        iv4 hA = __builtin_nontemporal_load(&H[j]);
        iv4 hB = __builtin_nontemporal_load(&H[j + n8]);
        iv4 rA = __builtin_nontemporal_load(&R[j]);
        iv4 rB = __builtin_nontemporal_load(&R[j + n8]);
        iv4 tA = __builtin_nontemporal_load(&T[j]);
        iv4 tB = __builtin_nontemporal_load(&T[j + n8]);
        GRP4(hA, rA, tA) GRP4(hB, rB, tB)
    }
#undef GRP4
#undef TESTQ

    // leftover elements [8*n8, N) — 0 for N=10M, kept for generality
    int rem = N - 8 * n8;
    if (blockIdx.x == 0 && (int)threadIdx.x < rem) {
        int j = 8 * n8 + threadIdx.x;
        uint32_t k = key32(dh[j], dr[j], dt[j]);
        if (k == EMPTY) *sent = 1u;
        else probe_mark(k, keys, flagbits, tmask);
    }

    // drain register queue (all waves concurrently -> latency hidden by TLP)
    if (cnt > 0) probe_mark(q0, keys, flagbits, tmask);
    if (cnt > 1) probe_mark(q1, keys, flagbits, tmask);
    if (cnt > 2) probe_mark(q2, keys, flagbits, tmask);
    if (cnt > 3) probe_mark(q3, keys, flagbits, tmask);
    if (cnt > 4) probe_mark(q4, keys, flagbits, tmask);
    if (cnt > 5) probe_mark(q5, keys, flagbits, tmask);
}

__global__ void k_out(const int* __restrict__ qh, const int* __restrict__ qr,
                      const int* __restrict__ qt,
                      const uint32_t* __restrict__ keys,
                      const uint32_t* __restrict__ flagbits,
                      const uint32_t* __restrict__ sent,
                      float* __restrict__ out, uint32_t tmask, int Q) {
    int i = blockIdx.x * blockDim.x + threadIdx.x;
    if (i >= Q) return;
    uint32_t key = key32(qh[i], qr[i], qt[i]);
    float v = -5.0f;
    if (key == EMPTY) {
        v = (*sent) ? 5.0f : -5.0f;
    } else {
        uint32_t slot = hash2(key) & tmask;
        while (true) {
            uint32_t kv = keys[slot];
            if (kv == key) { v = ((flagbits[slot >> 5] >> (slot & 31)) & 1u) ? 5.0f : -5.0f; break; }
            if (kv == EMPTY) break;
            slot = (slot + 1) & tmask;
        }
    }
    out[i] = v;
}

extern "C" void kernel_launch(void* const* d_in, const int* in_sizes, int n_in,
                              void* d_out, int out_size, void* d_ws, size_t ws_size,
                              hipStream_t stream) {
    const int* qh = (const int*)d_in[0];
    const int* qr = (const int*)d_in[1];
    const int* qt = (const int*)d_in[2];
    const int* data = (const int*)d_in[3];
    int Q = in_sizes[0];
    int N = in_sizes[3] / 3;
    const int* dh = data;
    const int* dr = data + (size_t)N;
    const int* dt = data + 2 * (size_t)N;
    float* out = (float*)d_out;

    int tb = 18;                               // 100K keys, alpha 0.38; floor 17 (livelock guard)
    size_t bloomB = (size_t)BWORDS * 4;        // 64 KB
    size_t need = bloomB + ((size_t)1 << (tb - 3)) + 256 + ((size_t)4 << tb);
    if (need > ws_size) tb = 17;
    size_t flagB = (size_t)1 << (tb - 3);
    uint32_t tmask = ((uint32_t)1 << tb) - 1u;

    uint32_t* bloom    = (uint32_t*)d_ws;
    uint32_t* flagbits = (uint32_t*)((char*)d_ws + bloomB);
    uint32_t* hdr      = (uint32_t*)((char*)d_ws + bloomB + flagB);     // sent@0
    uint32_t* keys     = (uint32_t*)((char*)d_ws + bloomB + flagB + 256);

    int zeroWords  = (int)((bloomB + flagB + 256) / 4);
    int totalWords = zeroWords + (1 << tb);
    k_zero<<<1024, 256, 0, stream>>>((uint32_t*)d_ws, zeroWords, totalWords);

    int qblocks = (Q + 255) / 256;
    k_insert<<<qblocks, 256, 0, stream>>>(qh, qr, qt, bloom, keys, tmask, Q);

    int n8 = N / 8;
    k_scan<<<512, TPB, 0, stream>>>(dh, dr, dt, bloom, keys, flagbits,
                                    hdr, tmask, n8, N);

    k_out<<<qblocks, 256, 0, stream>>>(qh, qr, qt, keys, flagbits, hdr, out, tmask, Q);
}